// Round 7
// baseline (232.833 us; speedup 1.0000x reference)
//
#include <hip/hip_runtime.h>
#include <math.h>

// Problem: inp [B=16, S=4096, D=512] fp32, lengths[16] int32.
// out [B,S,D+1]: channels 0..511 copy inp; channel 512 is
// pe[b,s] = cos(s/max(len_b,1)*pi) if s < len_b else 0.
//
// v7 = v3 + ONE change: __builtin_amdgcn_sched_barrier(0) between the
// load loop and the funnel/store loop.
//
// Why: v3 compiled to VGPR_Count=28 — but 8 in-flight float4 loads need
// 32 data VGPRs, so the "issue all loads first" ILP was provably
// destroyed by the pre-RA scheduler (it sank loads to minimize pressure,
// serializing the wave into {2 loads -> wait -> funnel -> store} x4).
// All 6 prior variants ran ~2KB-in-flight latency-bound at ~82us with
// every counter idle. The sched_barrier pins all 8 loads before any
// consumer: 8KB in flight per wave, counted vmcnt waits per chunk.
// VGPR stays <=64 -> still 8 waves/SIMD (occupancy unchanged).
//
// Funnel recap (on-device-verified in v3/v5): output chunk q (dwords
// 4q..4q+3) sources input dwords 4q-r..4q+3-r (r = floor(4q/513));
// those live in aligned input chunks si-1, si (si = q-(r>>2)); combine
// with funnel shift dlt = r&3. PE dword (c==512) sits at component dlt
// of its chunk; dirty chunks (c0>=509) patch it with cos and shift the
// tail by one.

#define PS   4096
#define PDO  513
#define PI_F 3.14159265358979323846f
#define OUT_V4 8404992   // 16*4096*513/4
#define IN_V4  8388608   // 16*4096*512/4
#define TPB  256
#define CPT  4           // chunks per thread

__global__ __launch_bounds__(TPB) void sinpe_kernel(
    const float* __restrict__ inp,
    const int* __restrict__ lengths,
    float* __restrict__ out)
{
    const float4* __restrict__ in4  = (const float4*)inp;
    float4* __restrict__       out4 = (float4*)out;

    const int q0 = blockIdx.x * (TPB * CPT) + threadIdx.x;

    float4 cur[CPT], prv[CPT];
    int r_[CPT], c0_[CPT];

    // ---- issue all 8 global loads; sched_barrier keeps them hoisted ----
#pragma unroll
    for (int k = 0; k < CPT; ++k) {
        const int q  = q0 + k * TPB;
        const int l0 = q << 2;                                   // out dword
        const int r  = (int)__umulhi((unsigned)l0, 8372256u);    // l0/513
        const int c0 = l0 - r * PDO;                             // 0..512
        const int si = q - (r >> 2);
        int ci = si;     if (ci > IN_V4 - 1) ci = IN_V4 - 1;     // last: cur unused
        int pi = si - 1; if (pi < 0)         pi = 0;             // q=0: prv unused
        cur[k] = in4[ci];
        prv[k] = in4[pi];
        r_[k] = r; c0_[k] = c0;
    }

    // Pin: no instruction may cross — all 8 loads issue before any
    // funnel/store, forcing their results simultaneously live (true
    // 8-deep VMEM pipeline; compiler emits counted vmcnt per chunk).
    __builtin_amdgcn_sched_barrier(0);

    // ---- funnel + store ----
#pragma unroll
    for (int k = 0; k < CPT; ++k) {
        const int q   = q0 + k * TPB;
        const int r   = r_[k];
        const int c0  = c0_[k];
        const int dlt = r & 3;

        // X[-4..-1] = prv, X[0..3] = cur; clean out[m] = X[m-dlt]
        const float px = prv[k].x, py = prv[k].y, pz = prv[k].z, pw = prv[k].w;
        const float cx = cur[k].x, cy = cur[k].y, cz = cur[k].z, cw = cur[k].w;
        const bool d2 = (dlt & 2) != 0;
        const bool d1 = (dlt & 1) != 0;
        const float Am1 = d2 ? py : pw;
        const float A0  = d2 ? pz : cx;
        const float A1  = d2 ? pw : cy;
        const float A2  = d2 ? cx : cz;
        const float A3  = d2 ? cy : cw;
        float w0 = d1 ? Am1 : A0;
        float w1 = d1 ? A0  : A1;
        float w2 = d1 ? A1  : A2;
        float w3 = d1 ? A2  : A3;

        if (c0 >= 509) {
            // chunk contains the PE dword (c==512) at component
            // mpe = 512-c0 == dlt; later components belong to row r+1.
            const int mpe = 512 - c0;
            const int b   = r >> 12;
            const int s   = r & (PS - 1);
            const int len = lengths[b];
            float pe = 0.0f;
            if (s < len)
                pe = cosf(((float)s / fmaxf((float)len, 1.0f)) * PI_F);
            const float n0 = (mpe == 0) ? pe : w0;
            const float n1 = (mpe == 1) ? pe : ((mpe < 1) ? w0 : w1);
            const float n2 = (mpe == 2) ? pe : ((mpe < 2) ? w1 : w2);
            const float n3 = (mpe == 3) ? pe : w2;
            w0 = n0; w1 = n1; w2 = n2; w3 = n3;
        }

        float4 o;
        o.x = w0; o.y = w1; o.z = w2; o.w = w3;
        out4[q] = o;                                  // aligned dwordx4
    }
}

extern "C" void kernel_launch(void* const* d_in, const int* in_sizes, int n_in,
                              void* d_out, int out_size, void* d_ws, size_t ws_size,
                              hipStream_t stream)
{
    const float* inp     = (const float*)d_in[0];
    const int*   lengths = (const int*)d_in[1];
    float*       out     = (float*)d_out;

    const int n_blocks = OUT_V4 / (TPB * CPT);  // 8208, exact (no tail)
    sinpe_kernel<<<n_blocks, TPB, 0, stream>>>(inp, lengths, out);
}